// Round 9
// baseline (244.987 us; speedup 1.0000x reference)
//
#include <hip/hip_runtime.h>
#include <hip/hip_bf16.h>

// MultiHeadMaskedSelfAttention: B=4 S=2048 D=1024 H=16 HD=64.
// fp32 in/out, bf16 internals. Pipeline: merged prepass (W->bf16^T, Wq
// pre-scaled by 0.125*log2e; X->bf16) | fused QKV GEMM (BK=64, T2-swizzled,
// LDS-bounce epilogue; V^T col-permuted) | flash attention (swapped QK^T,
// register P, 256 q-rows/block, 1-g2lds-per-wave dbuf staging) |
// output GEMM. WtO goes to ws spare when room (no d2d copy).
// ws = Q[16.8M] + V^T[16.8M] (+ Xb[16.8M] + WtO[2.1M] if ws_size allows);
// d_out(u16) = K[8.39M elems] + WtQ/K/V/O[4x1.05M elems].

typedef unsigned short u16;
typedef short bf16x8 __attribute__((ext_vector_type(8)));
typedef float f32x4 __attribute__((ext_vector_type(4)));

constexpr int NB = 4, NS = 2048, ND = 1024, NH = 16, NHD = 64;
constexpr int NM = NB * NS;  // 8192 rows
constexpr float NEG = -1e30f;
constexpr int EPAD = 136;    // gemm epilogue LDS stride (u16)
constexpr float KEXP = 0.125f * 1.4426950408889634f;  // 1/sqrt(64) * log2(e)

#if __has_builtin(__builtin_amdgcn_exp2f)
#define EXP2(x) __builtin_amdgcn_exp2f(x)
#else
#define EXP2(x) exp2f(x)
#endif

__device__ __forceinline__ u16 f2bf(float f) {
  union { float f; unsigned int u; } c; c.f = f;
  unsigned int r = (c.u + 0x7FFFu + ((c.u >> 16) & 1u)) >> 16;
  return (u16)r;
}
__device__ __forceinline__ unsigned int pk2bf(float a, float b) {
  float2 t; t.x = a; t.y = b;
  __hip_bfloat162 h = __float22bfloat162_rn(t);
  unsigned int u; __builtin_memcpy(&u, &h, 4); return u;
}
__device__ __forceinline__ void g2lds16(const u16* g, u16* l) {
  __builtin_amdgcn_global_load_lds(
      (const __attribute__((address_space(1))) void*)g,
      (__attribute__((address_space(3))) void*)l, 16, 0, 0);
}
// swizzled LDS fragment read: row-major [*][64] u16 tile, 16B chunk XOR (row&7)
__device__ __forceinline__ bf16x8 ldsw(const u16* b, int row, int cq) {
  return *(const bf16x8*)&b[row * 64 + ((cq ^ (row & 7)) << 3)];
}

__global__ __launch_bounds__(256) void fill_kernel(float* __restrict__ p, float v, int n) {
  int i = blockIdx.x * 256 + threadIdx.x;
  if (i < n) p[i] = v;
}

// Merged prepass. z<4: W [1024][1024] fp32 -> Wt [n][k] bf16 (transpose+cvt),
// z==0 (Wq) pre-scaled by KEXP. z==4: X fp32 -> Xb bf16 (grid-stride, 256 blk).
__global__ __launch_bounds__(256) void prep_kernel(
    const float* __restrict__ s0, const float* __restrict__ s1,
    const float* __restrict__ s2, const float* __restrict__ s3,
    u16* __restrict__ d0, u16* __restrict__ d1,
    u16* __restrict__ d2, u16* __restrict__ d3,
    const float* __restrict__ xin, u16* __restrict__ xout) {
  const int z = blockIdx.z;
  const int tid = threadIdx.x;
  if (z == 4) {  // X -> bf16, 256 blocks x 256 thr, grid-stride over n4 f4
    if (!xout) return;
    const int n4 = NM * ND / 4;
    int base = (blockIdx.y * 16 + blockIdx.x) * 256 + tid;
    for (int i = base; i < n4; i += 65536) {
      float4 f = ((const float4*)xin)[i];
      ushort4 o;
      o.x = f2bf(f.x); o.y = f2bf(f.y); o.z = f2bf(f.z); o.w = f2bf(f.w);
      ((ushort4*)xout)[i] = o;
    }
    return;
  }
  const float* S = (z == 0) ? s0 : (z == 1) ? s1 : (z == 2) ? s2 : s3;
  u16* D = (z == 0) ? d0 : (z == 1) ? d1 : (z == 2) ? d2 : d3;
  const float sc = (z == 0) ? KEXP : 1.0f;
  __shared__ u16 t[64][68];
  const int r0 = blockIdx.x * 64, c0 = blockIdx.y * 64;
#pragma unroll
  for (int i = 0; i < 4; i++) {
    int row = (tid >> 4) + i * 16;
    int col = (tid & 15) * 4;
    float4 f = *(const float4*)&S[(long)(r0 + row) * ND + c0 + col];
    ushort4 u;
    u.x = f2bf(f.x * sc); u.y = f2bf(f.y * sc);
    u.z = f2bf(f.z * sc); u.w = f2bf(f.w * sc);
    *(ushort4*)&t[row][col] = u;
  }
  __syncthreads();
#pragma unroll
  for (int i = 0; i < 4; i++) {
    int nrow = (tid >> 4) + i * 16;
    int kcol = (tid & 15) * 4;
    ushort4 u;
    u.x = t[kcol + 0][nrow]; u.y = t[kcol + 1][nrow];
    u.z = t[kcol + 2][nrow]; u.w = t[kcol + 3][nrow];
    *(ushort4*)&D[(long)(c0 + nrow) * ND + r0 + kcol] = u;
  }
}

// Fused QKV GEMM: Y[m, 3072] = X @ [Wq|Wk|Wv] + [bq|bk|bv].
// grid (64 m-tiles, 24 n-tiles); mat = ntile>>3 (0=Q,1=K,2=V). BK=64 (16 iters).
// LDS: A/B 128x64 u16 T2-swizzled. Epilogue bounces acc through a padded LDS
// tile -> coalesced stores. Q scale carried by pre-scaled Wq weights +
// KEXP-scaled bias. V^T written with per-32-col permutation so attn's packed
// P registers form a valid x32 B-fragment directly.
__global__ __launch_bounds__(256, 3) void gemm_qkv_kernel(
    const float* __restrict__ Xf, const u16* __restrict__ Xb,
    const u16* __restrict__ WtQ,
    const float* __restrict__ bqp, const float* __restrict__ bkp,
    const float* __restrict__ bvp,
    u16* __restrict__ Qw, u16* __restrict__ Kw, u16* __restrict__ Vtw,
    int xmode) {
  __shared__ __attribute__((aligned(16))) u16 SMEM[128 * EPAD];  // 34.8KB
  u16* Asm = SMEM;          // staging A: 128x64 u16 (16KB)
  u16* Bsm = SMEM + 8192;   // staging B: 128x64 u16 (16KB)
  const int m0 = blockIdx.x * 128;
  const int ng = blockIdx.y;
  const int mat = ng >> 3, n0 = (ng & 7) * 128;
  const u16* Wt = WtQ + (long)mat * ND * ND;
  const int tid = threadIdx.x;
  const int w = tid >> 6, lane = tid & 63, quad = lane >> 4, lr = lane & 15;
  const int wm = w & 1, wn = w >> 1;
  const int b_r = lane >> 3, b_c = lane & 7;  // staging: 8 rows x 8 chunks/wave

  f32x4 acc[4][4] = {};

  for (int k0 = 0; k0 < ND; k0 += 64) {
    __syncthreads();
    if (xmode == 0) {
#pragma unroll
      for (int j = 0; j < 4; j++) {
        int r = w * 32 + j * 8 + b_r;
        const float* src = Xf + (long)(m0 + r) * ND + k0 + ((b_c ^ (r & 7)) << 3);
        float4 f0 = *(const float4*)src;
        float4 f1 = *(const float4*)(src + 4);
        uint4 d;
        d.x = pk2bf(f0.x, f0.y); d.y = pk2bf(f0.z, f0.w);
        d.z = pk2bf(f1.x, f1.y); d.w = pk2bf(f1.z, f1.w);
        *(uint4*)&Asm[r * 64 + (b_c << 3)] = d;
      }
    } else {
#pragma unroll
      for (int j = 0; j < 4; j++) {
        int R0 = w * 32 + j * 8;
        int r = R0 + b_r;
        g2lds16(Xb + (long)(m0 + r) * ND + k0 + ((b_c ^ (r & 7)) << 3),
                &Asm[R0 * 64]);
      }
    }
#pragma unroll
    for (int j = 0; j < 4; j++) {
      int R0 = w * 32 + j * 8;
      int r = R0 + b_r;
      g2lds16(Wt + (long)(n0 + r) * ND + k0 + ((b_c ^ (r & 7)) << 3),
              &Bsm[R0 * 64]);
    }
    __syncthreads();

#pragma unroll
    for (int kk = 0; kk < 2; kk++) {
      bf16x8 af[4], bfr[4];
#pragma unroll
      for (int mt = 0; mt < 4; mt++)
        af[mt] = ldsw(Asm, wm * 64 + mt * 16 + lr, kk * 4 + quad);
#pragma unroll
      for (int nt = 0; nt < 4; nt++)
        bfr[nt] = ldsw(Bsm, wn * 64 + nt * 16 + lr, kk * 4 + quad);
#pragma unroll
      for (int nt = 0; nt < 4; nt++)
#pragma unroll
        for (int mt = 0; mt < 4; mt++)
          acc[nt][mt] = __builtin_amdgcn_mfma_f32_16x16x32_bf16(
              af[mt], bfr[nt], acc[nt][mt], 0, 0, 0);
    }
  }

  const float* bias = (mat == 0) ? bqp : (mat == 1) ? bkp : bvp;
  const float bsc = (mat == 0) ? KEXP : 1.0f;
  __syncthreads();  // staging LDS reuse
  if (mat < 2) {
    // LDS tile [m][n] (stride EPAD), scalar bf16 scatter, coalesced gather
#pragma unroll
    for (int nt = 0; nt < 4; nt++) {
      int n_loc = wn * 64 + nt * 16 + lr;
      float bn = bias[n0 + n_loc] * bsc;
#pragma unroll
      for (int mt = 0; mt < 4; mt++)
#pragma unroll
        for (int r = 0; r < 4; r++) {
          int m_loc = wm * 64 + mt * 16 + quad * 4 + r;
          SMEM[m_loc * EPAD + n_loc] = f2bf(acc[nt][mt][r] + bn);
        }
    }
    __syncthreads();
    u16* Yv = (mat == 0) ? Qw : Kw;
#pragma unroll
    for (int pass = 0; pass < 8; pass++) {
      int row = pass * 16 + (tid >> 4), c = tid & 15;
      uint4 d = *(const uint4*)&SMEM[row * EPAD + c * 8];
      int n_g = n0 + c * 8, h_ = n_g >> 6, hd_ = n_g & (NHD - 1);
      int m = m0 + row, b_ = m >> 11, s_ = m & (NS - 1);
      *(uint4*)&Yv[((long)((b_ * NH + h_) * NS + s_)) * NHD + hd_] = d;
    }
  } else {
    // LDS tile [n][m] (stride EPAD), packed b64 scatter, permuted gather
#pragma unroll
    for (int nt = 0; nt < 4; nt++) {
      int n_loc = wn * 64 + nt * 16 + lr;
      float bn = bias[n0 + n_loc];
#pragma unroll
      for (int mt = 0; mt < 4; mt++) {
        int m_base = wm * 64 + mt * 16 + quad * 4;
        uint2 d;
        d.x = pk2bf(acc[nt][mt][0] + bn, acc[nt][mt][1] + bn);
        d.y = pk2bf(acc[nt][mt][2] + bn, acc[nt][mt][3] + bn);
        *(uint2*)&SMEM[n_loc * EPAD + m_base] = d;
      }
    }
    __syncthreads();
#pragma unroll
    for (int pass = 0; pass < 8; pass++) {
      int plane = pass * 16 + (tid >> 4), mc = tid & 15;
      uint4 d = *(const uint4*)&SMEM[plane * EPAD + mc * 8];
      int n_g = n0 + plane, h_ = n_g >> 6, hd_ = n_g & (NHD - 1);
      int m = m0 + mc * 8, b_ = m >> 11, s_ = m & (NS - 1);
      long base = ((long)((b_ * NH + h_) * NHD + hd_)) * NS;
      int cb = s_ & ~31;
      int s1 = (mc & 1) * 16 + ((mc >> 1) & 1) * 4;  // perm of 8-group start
      uint2 lo; lo.x = d.x; lo.y = d.y;
      uint2 hi; hi.x = d.z; hi.y = d.w;
      *(uint2*)&Vtw[base + cb + s1] = lo;
      *(uint2*)&Vtw[base + cb + s1 + 8] = hi;
    }
  }
}

// Output GEMM: out[m,1024] = O(split-head bf16, gathered) @ WtO + bo, fp32.
// BK=64 (one head per K-tile), T2-swizzled staging; fp32 epilogue (coalesced).
__global__ __launch_bounds__(256, 3) void gemm_out_kernel(
    const u16* __restrict__ Xg, const u16* __restrict__ Wt,
    const float* __restrict__ bias, float* __restrict__ Y) {
  __shared__ __attribute__((aligned(16))) u16 Asm[128 * 64];
  __shared__ __attribute__((aligned(16))) u16 Bsm[128 * 64];
  const int m0 = blockIdx.x * 128, n0 = blockIdx.y * 128;
  const int tid = threadIdx.x;
  const int w = tid >> 6, lane = tid & 63, quad = lane >> 4, lr = lane & 15;
  const int wm = w & 1, wn = w >> 1;
  const int b_r = lane >> 3, b_c = lane & 7;

  f32x4 acc[4][4] = {};

  for (int k0 = 0; k0 < ND; k0 += 64) {
    __syncthreads();
    const int h_ = k0 >> 6;  // BK=64 == head size
#pragma unroll
    for (int j = 0; j < 4; j++) {
      int R0 = w * 32 + j * 8;
      int r = R0 + b_r;
      int mrow = m0 + r, b_ = mrow >> 11, s_ = mrow & (NS - 1);
      g2lds16(Xg + ((long)((b_ * NH + h_) * NS + s_)) * NHD + ((b_c ^ (r & 7)) << 3),
              &Asm[R0 * 64]);
      g2lds16(Wt + (long)(n0 + r) * ND + k0 + ((b_c ^ (r & 7)) << 3),
              &Bsm[R0 * 64]);
    }
    __syncthreads();

#pragma unroll
    for (int kk = 0; kk < 2; kk++) {
      bf16x8 af[4], bfr[4];
#pragma unroll
      for (int mt = 0; mt < 4; mt++)
        af[mt] = ldsw(Asm, wm * 64 + mt * 16 + lr, kk * 4 + quad);
#pragma unroll
      for (int nt = 0; nt < 4; nt++)
        bfr[nt] = ldsw(Bsm, wn * 64 + nt * 16 + lr, kk * 4 + quad);
#pragma unroll
      for (int nt = 0; nt < 4; nt++)
#pragma unroll
        for (int mt = 0; mt < 4; mt++)
          acc[nt][mt] = __builtin_amdgcn_mfma_f32_16x16x32_bf16(
              af[mt], bfr[nt], acc[nt][mt], 0, 0, 0);
    }
  }

#pragma unroll
  for (int nt = 0; nt < 4; nt++) {
    int n = n0 + wn * 64 + nt * 16 + lr;
    float bn = bias[n];
#pragma unroll
    for (int mt = 0; mt < 4; mt++) {
#pragma unroll
      for (int r = 0; r < 4; r++) {
        int m = m0 + wm * 64 + mt * 16 + quad * 4 + r;
        Y[(long)m * ND + n] = acc[nt][mt][r] + bn;
      }
    }
  }
}

// Flash attention, causal, no-max softmax; li via ones-MFMA (row-complete).
// Q (pre-scaled) / K [B,H,S,64] bf16; V^T [B*H,64,S] bf16 (col-permuted).
// Output in-place over Q. 256 q-rows/block, 16 waves (1024 thr): waves 0-7
// stage K, waves 8-15 stage V -- ONE g2lds per wave per tile. Double-buffered
// with counted vmcnt(1) (each wave has <=2 outstanding; 1 = own prev landed).
// Swapped QK^T, register-resident P (contraction-permutation invariance).
__global__ __launch_bounds__(1024) void attn_kernel(
    u16* __restrict__ Q, const u16* __restrict__ K, const u16* __restrict__ Vtg) {
  __shared__ __attribute__((aligned(16))) u16 Klds[2][64 * 64];
  __shared__ __attribute__((aligned(16))) u16 Vt[2][64 * 64];
  const int bh = blockIdx.x;
  const int qt = 7 - blockIdx.y;        // LPT: longest q-blocks first
  const int q0 = qt * 256;
  const int tid = threadIdx.x;
  const int w = tid >> 6, lane = tid & 63, quad = lane >> 4, lr = lane & 15;
  u16* Qb = Q + (long)bh * NS * NHD;
  const u16* Kb = K + (long)bh * NS * NHD;
  const u16* Vb = Vtg + (long)bh * NHD * NS;

  const int qw0 = q0 + w * 16;          // this wave's first q-row
  bf16x8 qf[2];
  {
    int m = qw0 + lr;
    qf[0] = *(const bf16x8*)&Qb[(long)m * NHD + quad * 8];
    qf[1] = *(const bf16x8*)&Qb[(long)m * NHD + 32 + quad * 8];
  }
  const bf16x8 ones = {0x3F80, 0x3F80, 0x3F80, 0x3F80,
                       0x3F80, 0x3F80, 0x3F80, 0x3F80};  // bf16 1.0 x8

  f32x4 oaccT[4] = {};                  // O^T: d=dt*16+quad*4+r, q=lr
  f32x4 lacc = {};                      // li[q=lr] (all r identical)

  const int sr = lane >> 3;                       // row in stripe (8 rows/wave)
  const int ssw = (((lane & 7) ^ sr) << 3);       // pre-swizzled source col
  const int krow0 = (w & 7) * 8;                  // staged stripe base
  const bool isK = w < 8;               // waves 0-7: K; 8-15: V
  const int ntile = q0 / 64 + 4;        // j-tiles: j0 = 0 .. q0+192

  // prologue: stage tile 0 into buf 0 (one g2lds per wave)
  if (isK) g2lds16(Kb + (long)(krow0 + sr) * NHD + ssw, &Klds[0][krow0 * 64]);
  else     g2lds16(Vb + (long)(krow0 + sr) * NS + 0 + ssw, &Vt[0][krow0 * 64]);

  for (int ti = 0; ti < ntile; ti++) {
    const int j0 = ti * 64;
    const int cur = ti & 1;
    if (ti + 1 < ntile) {  // issue next tile into the other buffer
      const int j1 = j0 + 64;
      if (isK)
        g2lds16(Kb + (long)(j1 + krow0 + sr) * NHD + ssw, &Klds[cur ^ 1][krow0 * 64]);
      else
        g2lds16(Vb + (long)(krow0 + sr) * NS + j1 + ssw, &Vt[cur ^ 1][krow0 * 64]);
      asm volatile("s_waitcnt vmcnt(1)" ::: "memory");  // own tile ti landed
    } else {
      asm volatile("s_waitcnt vmcnt(0)" ::: "memory");
    }
    __builtin_amdgcn_s_barrier();       // everyone's tile ti landed
    __builtin_amdgcn_sched_barrier(0);  // fence ds_read hoisting (rule 18)

    if (j0 <= qw0 + 15) {               // wave-uniform: skip fully-masked tile
      f32x4 scT[4] = {};                // P^T: k=t*16+quad*4+r, q=lr
#pragma unroll
      for (int t = 0; t < 4; t++) {
        int kr = t * 16 + lr;
        bf16x8 kf0 = ldsw(Klds[cur], kr, quad);
        bf16x8 kf1 = ldsw(Klds[cur], kr, 4 + quad);
        scT[t] = __builtin_amdgcn_mfma_f32_16x16x32_bf16(kf0, qf[0], scT[t], 0, 0, 0);
        scT[t] = __builtin_amdgcn_mfma_f32_16x16x32_bf16(kf1, qf[1], scT[t], 0, 0, 0);
      }

      if (j0 + 63 > qw0) {  // wave-uniform gate: tile straddles the diagonal
#pragma unroll
        for (int t = 0; t < 4; t++)
#pragma unroll
          for (int r = 0; r < 4; r++)
            if ((j0 + t * 16 + quad * 4 + r) > (qw0 + lr)) scT[t][r] = NEG;
      }

#pragma unroll
      for (int t = 0; t < 4; t++)
#pragma unroll
        for (int r = 0; r < 4; r++) scT[t][r] = EXP2(scT[t][r]);

#pragma unroll
      for (int kk = 0; kk < 2; kk++) {
        uint4 pu;
        pu.x = pk2bf(scT[2 * kk][0], scT[2 * kk][1]);
        pu.y = pk2bf(scT[2 * kk][2], scT[2 * kk][3]);
        pu.z = pk2bf(scT[2 * kk + 1][0], scT[2 * kk + 1][1]);
        pu.w = pk2bf(scT[2 * kk + 1][2], scT[2 * kk + 1][3]);
        bf16x8 pt; __builtin_memcpy(&pt, &pu, 16);
        lacc = __builtin_amdgcn_mfma_f32_16x16x32_bf16(ones, pt, lacc, 0, 0, 0);
#pragma unroll
        for (int dt = 0; dt < 4; dt++) {
          bf16x8 va = ldsw(Vt[cur], dt * 16 + lr, kk * 4 + quad);
          oaccT[dt] = __builtin_amdgcn_mfma_f32_16x16x32_bf16(va, pt, oaccT[dt], 0, 0, 0);
        }
      }
    }
    __builtin_amdgcn_s_barrier();       // readers done before buf overwrite
  }

  const float inv = 1.0f / lacc[0];     // full row-sum for q=lr
#pragma unroll
  for (int dt = 0; dt < 4; dt++) {
    uint2 o;
    o.x = pk2bf(oaccT[dt][0] * inv, oaccT[dt][1] * inv);
    o.y = pk2bf(oaccT[dt][2] * inv, oaccT[dt][3] * inv);
    *(uint2*)&Qb[(long)(qw0 + lr) * NHD + dt * 16 + quad * 4] = o;
  }
}

extern "C" void kernel_launch(void* const* d_in, const int* in_sizes, int n_in,
                              void* d_out, int out_size, void* d_ws, size_t ws_size,
                              hipStream_t stream) {
  const float* x  = (const float*)d_in[0];
  const float* Wq = (const float*)d_in[1];
  const float* bq = (const float*)d_in[2];
  const float* Wk = (const float*)d_in[3];
  const float* bk = (const float*)d_in[4];
  const float* Wv = (const float*)d_in[5];
  const float* bv = (const float*)d_in[6];
  const float* Wo = (const float*)d_in[7];
  const float* bo = (const float*)d_in[8];

  const size_t BUF = (size_t)NM * ND * sizeof(u16);   // 16.8 MB
  const size_t WSZ = (size_t)ND * ND * sizeof(u16);   // 2.1 MB
  if (ws_size < 2 * BUF) {  // never expected; safety
    fill_kernel<<<(out_size + 255) / 256, 256, 0, stream>>>((float*)d_out, 0.f, out_size);
    return;
  }

  u16* Qw  = (u16*)d_ws;                 // [B,H,S,64] bf16 (pre-scaled by KEXP)
  u16* Vtw = Qw + (long)NM * ND;         // V^T [B*H,64,S] bf16 (col-permuted)
  u16* Kw  = (u16*)d_out;                // K [B,H,S,64] bf16
  u16* WtQ = Kw + (long)NM * ND;         // W^T bf16 [n][k], 3x 1M elems
  u16* WtO = WtQ + 3L * ND * ND;         // d_out fallback slot for WtO
  const bool bigws = ws_size >= 3 * BUF; // room for bf16 X in ws
  u16* Xb = bigws ? (Vtw + (long)NM * ND) : nullptr;
  // WtO spare: beyond Xb, never clobbered -> gemm_out reads it directly.
  u16* spare = (ws_size >= 3 * BUF + WSZ) ? (Xb + (long)NM * ND) : nullptr;
  u16* wto_dst = spare ? spare : WtO;

  prep_kernel<<<dim3(16, 16, 5), 256, 0, stream>>>(
      Wq, Wk, Wv, Wo,
      WtQ, WtQ + (long)ND * ND, WtQ + 2L * ND * ND, wto_dst, x, Xb);

  gemm_qkv_kernel<<<dim3(64, 24), 256, 0, stream>>>(
      x, Xb, WtQ, bq, bk, bv, Qw, Kw, Vtw, bigws ? 2 : 0);
  attn_kernel<<<dim3(NB * NH, NS / 256), 1024, 0, stream>>>(Qw, Kw, Vtw);
  u16* wto_src;
  if (spare) {
    wto_src = spare;                     // no copy needed
  } else {
    hipMemcpyAsync(Vtw, WtO, WSZ, hipMemcpyDeviceToDevice, stream);
    wto_src = Vtw;
  }
  gemm_out_kernel<<<dim3(64, 8), 256, 0, stream>>>(Qw, wto_src, bo, (float*)d_out);
}

// Round 10
// 223.858 us; speedup vs baseline: 1.0944x; 1.0944x over previous
//
#include <hip/hip_runtime.h>
#include <hip/hip_bf16.h>

// MultiHeadMaskedSelfAttention: B=4 S=2048 D=1024 H=16 HD=64.
// fp32 in/out, bf16 internals. Pipeline: merged prepass (W->bf16^T, Wq
// pre-scaled by 0.125*log2e; X->bf16) | fused QKV GEMM (BK=64, T2-swizzled,
// LDS-bounce epilogue; V^T col-permuted) | flash attention (swapped QK^T,
// register P, 128 q-rows/block, 512 thr) | output GEMM.
// WtO goes to ws spare when room (no d2d copy).
// ws = Q[16.8M] + V^T[16.8M] (+ Xb[16.8M] + WtO[2.1M] if ws_size allows);
// d_out(u16) = K[8.39M elems] + WtQ/K/V/O[4x1.05M elems].

typedef unsigned short u16;
typedef short bf16x8 __attribute__((ext_vector_type(8)));
typedef float f32x4 __attribute__((ext_vector_type(4)));

constexpr int NB = 4, NS = 2048, ND = 1024, NH = 16, NHD = 64;
constexpr int NM = NB * NS;  // 8192 rows
constexpr float NEG = -1e30f;
constexpr int EPAD = 136;    // gemm epilogue LDS stride (u16)
constexpr float KEXP = 0.125f * 1.4426950408889634f;  // 1/sqrt(64) * log2(e)

#if __has_builtin(__builtin_amdgcn_exp2f)
#define EXP2(x) __builtin_amdgcn_exp2f(x)
#else
#define EXP2(x) exp2f(x)
#endif

__device__ __forceinline__ u16 f2bf(float f) {
  union { float f; unsigned int u; } c; c.f = f;
  unsigned int r = (c.u + 0x7FFFu + ((c.u >> 16) & 1u)) >> 16;
  return (u16)r;
}
__device__ __forceinline__ unsigned int pk2bf(float a, float b) {
  float2 t; t.x = a; t.y = b;
  __hip_bfloat162 h = __float22bfloat162_rn(t);
  unsigned int u; __builtin_memcpy(&u, &h, 4); return u;
}
__device__ __forceinline__ void g2lds16(const u16* g, u16* l) {
  __builtin_amdgcn_global_load_lds(
      (const __attribute__((address_space(1))) void*)g,
      (__attribute__((address_space(3))) void*)l, 16, 0, 0);
}
// swizzled LDS fragment read: row-major [*][64] u16 tile, 16B chunk XOR (row&7)
__device__ __forceinline__ bf16x8 ldsw(const u16* b, int row, int cq) {
  return *(const bf16x8*)&b[row * 64 + ((cq ^ (row & 7)) << 3)];
}

__global__ __launch_bounds__(256) void fill_kernel(float* __restrict__ p, float v, int n) {
  int i = blockIdx.x * 256 + threadIdx.x;
  if (i < n) p[i] = v;
}

// Merged prepass. z<4: W [1024][1024] fp32 -> Wt [n][k] bf16 (transpose+cvt),
// z==0 (Wq) pre-scaled by KEXP. z==4: X fp32 -> Xb bf16 (grid-stride, 256 blk).
__global__ __launch_bounds__(256) void prep_kernel(
    const float* __restrict__ s0, const float* __restrict__ s1,
    const float* __restrict__ s2, const float* __restrict__ s3,
    u16* __restrict__ d0, u16* __restrict__ d1,
    u16* __restrict__ d2, u16* __restrict__ d3,
    const float* __restrict__ xin, u16* __restrict__ xout) {
  const int z = blockIdx.z;
  const int tid = threadIdx.x;
  if (z == 4) {  // X -> bf16, 256 blocks x 256 thr, grid-stride over n4 f4
    if (!xout) return;
    const int n4 = NM * ND / 4;
    int base = (blockIdx.y * 16 + blockIdx.x) * 256 + tid;
    for (int i = base; i < n4; i += 65536) {
      float4 f = ((const float4*)xin)[i];
      ushort4 o;
      o.x = f2bf(f.x); o.y = f2bf(f.y); o.z = f2bf(f.z); o.w = f2bf(f.w);
      ((ushort4*)xout)[i] = o;
    }
    return;
  }
  const float* S = (z == 0) ? s0 : (z == 1) ? s1 : (z == 2) ? s2 : s3;
  u16* D = (z == 0) ? d0 : (z == 1) ? d1 : (z == 2) ? d2 : d3;
  const float sc = (z == 0) ? KEXP : 1.0f;
  __shared__ u16 t[64][68];
  const int r0 = blockIdx.x * 64, c0 = blockIdx.y * 64;
#pragma unroll
  for (int i = 0; i < 4; i++) {
    int row = (tid >> 4) + i * 16;
    int col = (tid & 15) * 4;
    float4 f = *(const float4*)&S[(long)(r0 + row) * ND + c0 + col];
    ushort4 u;
    u.x = f2bf(f.x * sc); u.y = f2bf(f.y * sc);
    u.z = f2bf(f.z * sc); u.w = f2bf(f.w * sc);
    *(ushort4*)&t[row][col] = u;
  }
  __syncthreads();
#pragma unroll
  for (int i = 0; i < 4; i++) {
    int nrow = (tid >> 4) + i * 16;
    int kcol = (tid & 15) * 4;
    ushort4 u;
    u.x = t[kcol + 0][nrow]; u.y = t[kcol + 1][nrow];
    u.z = t[kcol + 2][nrow]; u.w = t[kcol + 3][nrow];
    *(ushort4*)&D[(long)(c0 + nrow) * ND + r0 + kcol] = u;
  }
}

// Fused QKV GEMM: Y[m, 3072] = X @ [Wq|Wk|Wv] + [bq|bk|bv].
// grid (64 m-tiles, 24 n-tiles); mat = ntile>>3 (0=Q,1=K,2=V). BK=64 (16 iters).
// LDS: A/B 128x64 u16 T2-swizzled. Epilogue bounces acc through a padded LDS
// tile -> coalesced stores. Q scale carried by pre-scaled Wq weights +
// KEXP-scaled bias. V^T written with per-32-col permutation so attn's packed
// P registers form a valid x32 B-fragment directly.
__global__ __launch_bounds__(256, 3) void gemm_qkv_kernel(
    const float* __restrict__ Xf, const u16* __restrict__ Xb,
    const u16* __restrict__ WtQ,
    const float* __restrict__ bqp, const float* __restrict__ bkp,
    const float* __restrict__ bvp,
    u16* __restrict__ Qw, u16* __restrict__ Kw, u16* __restrict__ Vtw,
    int xmode) {
  __shared__ __attribute__((aligned(16))) u16 SMEM[128 * EPAD];  // 34.8KB
  u16* Asm = SMEM;          // staging A: 128x64 u16 (16KB)
  u16* Bsm = SMEM + 8192;   // staging B: 128x64 u16 (16KB)
  const int m0 = blockIdx.x * 128;
  const int ng = blockIdx.y;
  const int mat = ng >> 3, n0 = (ng & 7) * 128;
  const u16* Wt = WtQ + (long)mat * ND * ND;
  const int tid = threadIdx.x;
  const int w = tid >> 6, lane = tid & 63, quad = lane >> 4, lr = lane & 15;
  const int wm = w & 1, wn = w >> 1;
  const int b_r = lane >> 3, b_c = lane & 7;  // staging: 8 rows x 8 chunks/wave

  f32x4 acc[4][4] = {};

  for (int k0 = 0; k0 < ND; k0 += 64) {
    __syncthreads();
    if (xmode == 0) {
#pragma unroll
      for (int j = 0; j < 4; j++) {
        int r = w * 32 + j * 8 + b_r;
        const float* src = Xf + (long)(m0 + r) * ND + k0 + ((b_c ^ (r & 7)) << 3);
        float4 f0 = *(const float4*)src;
        float4 f1 = *(const float4*)(src + 4);
        uint4 d;
        d.x = pk2bf(f0.x, f0.y); d.y = pk2bf(f0.z, f0.w);
        d.z = pk2bf(f1.x, f1.y); d.w = pk2bf(f1.z, f1.w);
        *(uint4*)&Asm[r * 64 + (b_c << 3)] = d;
      }
    } else {
#pragma unroll
      for (int j = 0; j < 4; j++) {
        int R0 = w * 32 + j * 8;
        int r = R0 + b_r;
        g2lds16(Xb + (long)(m0 + r) * ND + k0 + ((b_c ^ (r & 7)) << 3),
                &Asm[R0 * 64]);
      }
    }
#pragma unroll
    for (int j = 0; j < 4; j++) {
      int R0 = w * 32 + j * 8;
      int r = R0 + b_r;
      g2lds16(Wt + (long)(n0 + r) * ND + k0 + ((b_c ^ (r & 7)) << 3),
              &Bsm[R0 * 64]);
    }
    __syncthreads();

#pragma unroll
    for (int kk = 0; kk < 2; kk++) {
      bf16x8 af[4], bfr[4];
#pragma unroll
      for (int mt = 0; mt < 4; mt++)
        af[mt] = ldsw(Asm, wm * 64 + mt * 16 + lr, kk * 4 + quad);
#pragma unroll
      for (int nt = 0; nt < 4; nt++)
        bfr[nt] = ldsw(Bsm, wn * 64 + nt * 16 + lr, kk * 4 + quad);
#pragma unroll
      for (int nt = 0; nt < 4; nt++)
#pragma unroll
        for (int mt = 0; mt < 4; mt++)
          acc[nt][mt] = __builtin_amdgcn_mfma_f32_16x16x32_bf16(
              af[mt], bfr[nt], acc[nt][mt], 0, 0, 0);
    }
  }

  const float* bias = (mat == 0) ? bqp : (mat == 1) ? bkp : bvp;
  const float bsc = (mat == 0) ? KEXP : 1.0f;
  __syncthreads();  // staging LDS reuse
  if (mat < 2) {
    // LDS tile [m][n] (stride EPAD), scalar bf16 scatter, coalesced gather
#pragma unroll
    for (int nt = 0; nt < 4; nt++) {
      int n_loc = wn * 64 + nt * 16 + lr;
      float bn = bias[n0 + n_loc] * bsc;
#pragma unroll
      for (int mt = 0; mt < 4; mt++)
#pragma unroll
        for (int r = 0; r < 4; r++) {
          int m_loc = wm * 64 + mt * 16 + quad * 4 + r;
          SMEM[m_loc * EPAD + n_loc] = f2bf(acc[nt][mt][r] + bn);
        }
    }
    __syncthreads();
    u16* Yv = (mat == 0) ? Qw : Kw;
#pragma unroll
    for (int pass = 0; pass < 8; pass++) {
      int row = pass * 16 + (tid >> 4), c = tid & 15;
      uint4 d = *(const uint4*)&SMEM[row * EPAD + c * 8];
      int n_g = n0 + c * 8, h_ = n_g >> 6, hd_ = n_g & (NHD - 1);
      int m = m0 + row, b_ = m >> 11, s_ = m & (NS - 1);
      *(uint4*)&Yv[((long)((b_ * NH + h_) * NS + s_)) * NHD + hd_] = d;
    }
  } else {
    // LDS tile [n][m] (stride EPAD), packed b64 scatter, permuted gather
#pragma unroll
    for (int nt = 0; nt < 4; nt++) {
      int n_loc = wn * 64 + nt * 16 + lr;
      float bn = bias[n0 + n_loc];
#pragma unroll
      for (int mt = 0; mt < 4; mt++) {
        int m_base = wm * 64 + mt * 16 + quad * 4;
        uint2 d;
        d.x = pk2bf(acc[nt][mt][0] + bn, acc[nt][mt][1] + bn);
        d.y = pk2bf(acc[nt][mt][2] + bn, acc[nt][mt][3] + bn);
        *(uint2*)&SMEM[n_loc * EPAD + m_base] = d;
      }
    }
    __syncthreads();
#pragma unroll
    for (int pass = 0; pass < 8; pass++) {
      int plane = pass * 16 + (tid >> 4), mc = tid & 15;
      uint4 d = *(const uint4*)&SMEM[plane * EPAD + mc * 8];
      int n_g = n0 + plane, h_ = n_g >> 6, hd_ = n_g & (NHD - 1);
      int m = m0 + mc * 8, b_ = m >> 11, s_ = m & (NS - 1);
      long base = ((long)((b_ * NH + h_) * NHD + hd_)) * NS;
      int cb = s_ & ~31;
      int s1 = (mc & 1) * 16 + ((mc >> 1) & 1) * 4;  // perm of 8-group start
      uint2 lo; lo.x = d.x; lo.y = d.y;
      uint2 hi; hi.x = d.z; hi.y = d.w;
      *(uint2*)&Vtw[base + cb + s1] = lo;
      *(uint2*)&Vtw[base + cb + s1 + 8] = hi;
    }
  }
}

// Output GEMM: out[m,1024] = O(split-head bf16, gathered) @ WtO + bo, fp32.
// BK=64 (one head per K-tile), T2-swizzled staging; fp32 epilogue (coalesced).
__global__ __launch_bounds__(256, 3) void gemm_out_kernel(
    const u16* __restrict__ Xg, const u16* __restrict__ Wt,
    const float* __restrict__ bias, float* __restrict__ Y) {
  __shared__ __attribute__((aligned(16))) u16 Asm[128 * 64];
  __shared__ __attribute__((aligned(16))) u16 Bsm[128 * 64];
  const int m0 = blockIdx.x * 128, n0 = blockIdx.y * 128;
  const int tid = threadIdx.x;
  const int w = tid >> 6, lane = tid & 63, quad = lane >> 4, lr = lane & 15;
  const int wm = w & 1, wn = w >> 1;
  const int b_r = lane >> 3, b_c = lane & 7;

  f32x4 acc[4][4] = {};

  for (int k0 = 0; k0 < ND; k0 += 64) {
    __syncthreads();
    const int h_ = k0 >> 6;  // BK=64 == head size
#pragma unroll
    for (int j = 0; j < 4; j++) {
      int R0 = w * 32 + j * 8;
      int r = R0 + b_r;
      int mrow = m0 + r, b_ = mrow >> 11, s_ = mrow & (NS - 1);
      g2lds16(Xg + ((long)((b_ * NH + h_) * NS + s_)) * NHD + ((b_c ^ (r & 7)) << 3),
              &Asm[R0 * 64]);
      g2lds16(Wt + (long)(n0 + r) * ND + k0 + ((b_c ^ (r & 7)) << 3),
              &Bsm[R0 * 64]);
    }
    __syncthreads();

#pragma unroll
    for (int kk = 0; kk < 2; kk++) {
      bf16x8 af[4], bfr[4];
#pragma unroll
      for (int mt = 0; mt < 4; mt++)
        af[mt] = ldsw(Asm, wm * 64 + mt * 16 + lr, kk * 4 + quad);
#pragma unroll
      for (int nt = 0; nt < 4; nt++)
        bfr[nt] = ldsw(Bsm, wn * 64 + nt * 16 + lr, kk * 4 + quad);
#pragma unroll
      for (int nt = 0; nt < 4; nt++)
#pragma unroll
        for (int mt = 0; mt < 4; mt++)
          acc[nt][mt] = __builtin_amdgcn_mfma_f32_16x16x32_bf16(
              af[mt], bfr[nt], acc[nt][mt], 0, 0, 0);
    }
  }

#pragma unroll
  for (int nt = 0; nt < 4; nt++) {
    int n = n0 + wn * 64 + nt * 16 + lr;
    float bn = bias[n];
#pragma unroll
    for (int mt = 0; mt < 4; mt++) {
#pragma unroll
      for (int r = 0; r < 4; r++) {
        int m = m0 + wm * 64 + mt * 16 + quad * 4 + r;
        Y[(long)m * ND + n] = acc[nt][mt][r] + bn;
      }
    }
  }
}

// Flash attention, causal, no-max softmax; li via ones-MFMA (row-complete).
// Q (pre-scaled) / K [B,H,S,64] bf16; V^T [B*H,64,S] bf16 (col-permuted).
// Output in-place over Q. 128 q-rows/block, 8 waves (512 thr). Swapped QK^T:
// scT = mfma(K,Q) holds P^T with k=quad*4+r, q=lr. P stays in registers
// (contraction-permutation invariance). K/V staged via g2lds16 (pre-swizzled
// source cols, linear 64-stride LDS, XOR-swizzled reads). [r6-verified]
__global__ __launch_bounds__(512) void attn_kernel(
    u16* __restrict__ Q, const u16* __restrict__ K, const u16* __restrict__ Vtg) {
  __shared__ __attribute__((aligned(16))) u16 Klds[64 * 64];
  __shared__ __attribute__((aligned(16))) u16 Vt[64 * 64];
  const int bh = blockIdx.x;
  const int qt = 15 - blockIdx.y;       // LPT: longest q-blocks first
  const int q0 = qt * 128;
  const int tid = threadIdx.x;
  const int w = tid >> 6, lane = tid & 63, quad = lane >> 4, lr = lane & 15;
  u16* Qb = Q + (long)bh * NS * NHD;
  const u16* Kb = K + (long)bh * NS * NHD;
  const u16* Vb = Vtg + (long)bh * NHD * NS;

  const int qw0 = q0 + w * 16;          // this wave's first q-row
  bf16x8 qf[2];
  {
    int m = qw0 + lr;
    qf[0] = *(const bf16x8*)&Qb[(long)m * NHD + quad * 8];
    qf[1] = *(const bf16x8*)&Qb[(long)m * NHD + 32 + quad * 8];
  }
  const bf16x8 ones = {0x3F80, 0x3F80, 0x3F80, 0x3F80,
                       0x3F80, 0x3F80, 0x3F80, 0x3F80};  // bf16 1.0 x8

  f32x4 oaccT[4] = {};                  // O^T: d=dt*16+quad*4+r, q=lr
  f32x4 lacc = {};                      // li[q=lr] (all r identical)

  const int sr = lane >> 3;                       // row in wave's 8-row stripe
  const int ssw = (((lane & 7) ^ sr) << 3);       // pre-swizzled source col
  const int krow0 = w * 8;
  const int jmax = q0 + 64;             // last k-tile containing row q0+127

  for (int j0 = 0; j0 <= jmax; j0 += 64) {
    __syncthreads();
    g2lds16(Kb + (long)(j0 + krow0 + sr) * NHD + ssw, &Klds[krow0 * 64]);
    g2lds16(Vb + (long)(krow0 + sr) * NS + j0 + ssw, &Vt[krow0 * 64]);
    __syncthreads();

    if (j0 > qw0 + 15) continue;        // wave-uniform: fully masked tile

    f32x4 scT[4] = {};                  // P^T: k=t*16+quad*4+r, q=lr
#pragma unroll
    for (int t = 0; t < 4; t++) {
      int kr = t * 16 + lr;
      bf16x8 kf0 = ldsw(Klds, kr, quad);
      bf16x8 kf1 = ldsw(Klds, kr, 4 + quad);
      scT[t] = __builtin_amdgcn_mfma_f32_16x16x32_bf16(kf0, qf[0], scT[t], 0, 0, 0);
      scT[t] = __builtin_amdgcn_mfma_f32_16x16x32_bf16(kf1, qf[1], scT[t], 0, 0, 0);
    }

    if (j0 + 63 > qw0) {  // wave-uniform gate: tile straddles the diagonal
#pragma unroll
      for (int t = 0; t < 4; t++)
#pragma unroll
        for (int r = 0; r < 4; r++)
          if ((j0 + t * 16 + quad * 4 + r) > (qw0 + lr)) scT[t][r] = NEG;
    }

#pragma unroll
    for (int t = 0; t < 4; t++)
#pragma unroll
      for (int r = 0; r < 4; r++) scT[t][r] = EXP2(scT[t][r]);

#pragma unroll
    for (int kk = 0; kk < 2; kk++) {
      uint4 pu;
      pu.x = pk2bf(scT[2 * kk][0], scT[2 * kk][1]);
      pu.y = pk2bf(scT[2 * kk][2], scT[2 * kk][3]);
      pu.z = pk2bf(scT[2 * kk + 1][0], scT[2 * kk + 1][1]);
      pu.w = pk2bf(scT[2 * kk + 1][2], scT[2 * kk + 1][3]);
      bf16x8 pt; __builtin_memcpy(&pt, &pu, 16);
      lacc = __builtin_amdgcn_mfma_f32_16x16x32_bf16(ones, pt, lacc, 0, 0, 0);
#pragma unroll
      for (int dt = 0; dt < 4; dt++) {
        bf16x8 va = ldsw(Vt, dt * 16 + lr, kk * 4 + quad);
        oaccT[dt] = __builtin_amdgcn_mfma_f32_16x16x32_bf16(va, pt, oaccT[dt], 0, 0, 0);
      }
    }
  }

  const float inv = 1.0f / lacc[0];     // full row-sum for q=lr
#pragma unroll
  for (int dt = 0; dt < 4; dt++) {
    uint2 o;
    o.x = pk2bf(oaccT[dt][0] * inv, oaccT[dt][1] * inv);
    o.y = pk2bf(oaccT[dt][2] * inv, oaccT[dt][3] * inv);
    *(uint2*)&Qb[(long)(qw0 + lr) * NHD + dt * 16 + quad * 4] = o;
  }
}

extern "C" void kernel_launch(void* const* d_in, const int* in_sizes, int n_in,
                              void* d_out, int out_size, void* d_ws, size_t ws_size,
                              hipStream_t stream) {
  const float* x  = (const float*)d_in[0];
  const float* Wq = (const float*)d_in[1];
  const float* bq = (const float*)d_in[2];
  const float* Wk = (const float*)d_in[3];
  const float* bk = (const float*)d_in[4];
  const float* Wv = (const float*)d_in[5];
  const float* bv = (const float*)d_in[6];
  const float* Wo = (const float*)d_in[7];
  const float* bo = (const float*)d_in[8];

  const size_t BUF = (size_t)NM * ND * sizeof(u16);   // 16.8 MB
  const size_t WSZ = (size_t)ND * ND * sizeof(u16);   // 2.1 MB
  if (ws_size < 2 * BUF) {  // never expected; safety
    fill_kernel<<<(out_size + 255) / 256, 256, 0, stream>>>((float*)d_out, 0.f, out_size);
    return;
  }

  u16* Qw  = (u16*)d_ws;                 // [B,H,S,64] bf16 (pre-scaled by KEXP)
  u16* Vtw = Qw + (long)NM * ND;         // V^T [B*H,64,S] bf16 (col-permuted)
  u16* Kw  = (u16*)d_out;                // K [B,H,S,64] bf16
  u16* WtQ = Kw + (long)NM * ND;         // W^T bf16 [n][k], 3x 1M elems
  u16* WtO = WtQ + 3L * ND * ND;         // d_out fallback slot for WtO
  const bool bigws = ws_size >= 3 * BUF; // room for bf16 X in ws
  u16* Xb = bigws ? (Vtw + (long)NM * ND) : nullptr;
  // WtO spare: beyond Xb, never clobbered -> gemm_out reads it directly.
  u16* spare = (ws_size >= 3 * BUF + WSZ) ? (Xb + (long)NM * ND) : nullptr;
  u16* wto_dst = spare ? spare : WtO;

  prep_kernel<<<dim3(16, 16, 5), 256, 0, stream>>>(
      Wq, Wk, Wv, Wo,
      WtQ, WtQ + (long)ND * ND, WtQ + 2L * ND * ND, wto_dst, x, Xb);

  gemm_qkv_kernel<<<dim3(64, 24), 256, 0, stream>>>(
      x, Xb, WtQ, bq, bk, bv, Qw, Kw, Vtw, bigws ? 2 : 0);
  attn_kernel<<<dim3(NB * NH, NS / 128), 512, 0, stream>>>(Qw, Kw, Vtw);
  u16* wto_src;
  if (spare) {
    wto_src = spare;                     // no copy needed
  } else {
    hipMemcpyAsync(Vtw, WtO, WSZ, hipMemcpyDeviceToDevice, stream);
    wto_src = Vtw;
  }
  gemm_out_kernel<<<dim3(64, 8), 256, 0, stream>>>(Qw, wto_src, bo, (float*)d_out);
}